// Round 1
// baseline (48055.344 us; speedup 1.0000x reference)
//
#include <hip/hip_runtime.h>
#include <math.h>

#define B_ 32
#define T_ 512
#define D_ 1024
#define H_ 1024

__device__ __forceinline__ float sigm(float x) { return 1.0f / (1.0f + __expf(-x)); }

// One timestep: gates[b, q*H+j] = x_t[b,:]·Wx[q*H+j,:] + h_{t-1}[b,:]·Wh[q*H+j,:] + bx + bh
// grid: 256 blocks (4 j-columns each), block: 256 threads.
// wave layout: lane = khalf + 2*b  (32 batches x 2 k-halves), wave id = jj (4 per block).
__global__ __launch_bounds__(256) void lstm_step(
    const float* __restrict__ inp,   // [B,T,D]
    const float* __restrict__ Wx,    // [4H,D]
    const float* __restrict__ bx,    // [4H]
    const float* __restrict__ Wh,    // [4H,H]
    const float* __restrict__ bh,    // [4H]
    float* __restrict__ out,         // [B,T,H] — also serves as h_{t-1} source
    float* __restrict__ c_state,     // [B,H] in d_ws
    int t)
{
    const int tid   = threadIdx.x;
    const int lane  = tid & 63;
    const int khalf = lane & 1;
    const int b     = lane >> 1;          // 0..31
    const int wv    = tid >> 6;           // 0..3
    const int j     = blockIdx.x * 4 + wv; // 0..1023

    const int k0 = khalf * (D_ / 2);

    float a0 = 0.f, a1 = 0.f, a2 = 0.f, a3 = 0.f;

    // ---- x-projection part: dot(x_t[b, k0:k0+512], Wx[q*H+j, k0:k0+512]) ----
    {
        const float* __restrict__ xrow = inp + ((size_t)b * T_ + t) * D_ + k0;
        const float* __restrict__ w0 = Wx + ((size_t)(0 * H_ + j)) * D_ + k0;
        const float* __restrict__ w1 = Wx + ((size_t)(1 * H_ + j)) * D_ + k0;
        const float* __restrict__ w2 = Wx + ((size_t)(2 * H_ + j)) * D_ + k0;
        const float* __restrict__ w3 = Wx + ((size_t)(3 * H_ + j)) * D_ + k0;
        #pragma unroll 2
        for (int kk = 0; kk < D_ / 2; kk += 4) {
            const float4 xv = *reinterpret_cast<const float4*>(xrow + kk);
            const float4 v0 = *reinterpret_cast<const float4*>(w0 + kk);
            const float4 v1 = *reinterpret_cast<const float4*>(w1 + kk);
            const float4 v2 = *reinterpret_cast<const float4*>(w2 + kk);
            const float4 v3 = *reinterpret_cast<const float4*>(w3 + kk);
            a0 = fmaf(xv.x, v0.x, fmaf(xv.y, v0.y, fmaf(xv.z, v0.z, fmaf(xv.w, v0.w, a0))));
            a1 = fmaf(xv.x, v1.x, fmaf(xv.y, v1.y, fmaf(xv.z, v1.z, fmaf(xv.w, v1.w, a1))));
            a2 = fmaf(xv.x, v2.x, fmaf(xv.y, v2.y, fmaf(xv.z, v2.z, fmaf(xv.w, v2.w, a2))));
            a3 = fmaf(xv.x, v3.x, fmaf(xv.y, v3.y, fmaf(xv.z, v3.z, fmaf(xv.w, v3.w, a3))));
        }
    }

    // ---- recurrent part: dot(h_{t-1}[b, :], Wh[q*H+j, :])  (h0 = 0 → skip at t==0) ----
    if (t > 0) {
        const float* __restrict__ hrow = out + ((size_t)b * T_ + (t - 1)) * H_ + khalf * (H_ / 2);
        const float* __restrict__ w0 = Wh + ((size_t)(0 * H_ + j)) * H_ + khalf * (H_ / 2);
        const float* __restrict__ w1 = Wh + ((size_t)(1 * H_ + j)) * H_ + khalf * (H_ / 2);
        const float* __restrict__ w2 = Wh + ((size_t)(2 * H_ + j)) * H_ + khalf * (H_ / 2);
        const float* __restrict__ w3 = Wh + ((size_t)(3 * H_ + j)) * H_ + khalf * (H_ / 2);
        #pragma unroll 2
        for (int kk = 0; kk < H_ / 2; kk += 4) {
            const float4 hv = *reinterpret_cast<const float4*>(hrow + kk);
            const float4 v0 = *reinterpret_cast<const float4*>(w0 + kk);
            const float4 v1 = *reinterpret_cast<const float4*>(w1 + kk);
            const float4 v2 = *reinterpret_cast<const float4*>(w2 + kk);
            const float4 v3 = *reinterpret_cast<const float4*>(w3 + kk);
            a0 = fmaf(hv.x, v0.x, fmaf(hv.y, v0.y, fmaf(hv.z, v0.z, fmaf(hv.w, v0.w, a0))));
            a1 = fmaf(hv.x, v1.x, fmaf(hv.y, v1.y, fmaf(hv.z, v1.z, fmaf(hv.w, v1.w, a1))));
            a2 = fmaf(hv.x, v2.x, fmaf(hv.y, v2.y, fmaf(hv.z, v2.z, fmaf(hv.w, v2.w, a2))));
            a3 = fmaf(hv.x, v3.x, fmaf(hv.y, v3.y, fmaf(hv.z, v3.z, fmaf(hv.w, v3.w, a3))));
        }
    }

    // ---- combine the two k-halves (partner lane) ----
    a0 += __shfl_xor(a0, 1, 64);
    a1 += __shfl_xor(a1, 1, 64);
    a2 += __shfl_xor(a2, 1, 64);
    a3 += __shfl_xor(a3, 1, 64);

    // ---- gates + state update (even lanes only) ----
    if (khalf == 0) {
        const float gi = sigm(a0 + bx[0 * H_ + j] + bh[0 * H_ + j]);
        const float gf = sigm(a1 + bx[1 * H_ + j] + bh[1 * H_ + j]);
        const float gg = sigm(a2 + bx[2 * H_ + j] + bh[2 * H_ + j]);  // NOTE: sigmoid, per reference
        const float go = sigm(a3 + bx[3 * H_ + j] + bh[3 * H_ + j]);

        const size_t ci = (size_t)b * H_ + j;
        float c = (t > 0) ? c_state[ci] : 0.0f;
        c = c * gf + gi * gg;
        c_state[ci] = c;
        out[((size_t)b * T_ + t) * H_ + j] = go * tanhf(c);
    }
}

extern "C" void kernel_launch(void* const* d_in, const int* in_sizes, int n_in,
                              void* d_out, int out_size, void* d_ws, size_t ws_size,
                              hipStream_t stream) {
    const float* inp = (const float*)d_in[0];
    const float* Wx  = (const float*)d_in[1];
    const float* bx  = (const float*)d_in[2];
    const float* Wh  = (const float*)d_in[3];
    const float* bh  = (const float*)d_in[4];
    float* out = (float*)d_out;
    float* c_state = (float*)d_ws;   // 32*1024*4 = 128 KB

    dim3 grid(H_ / 4);   // 256 blocks
    dim3 block(256);
    for (int t = 0; t < T_; ++t) {
        lstm_step<<<grid, block, 0, stream>>>(inp, Wx, bx, Wh, bh, out, c_state, t);
    }
}

// Round 2
// 7622.961 us; speedup vs baseline: 6.3040x; 6.3040x over previous
//
#include <hip/hip_runtime.h>
#include <hip/hip_bf16.h>
#include <math.h>

#define B_ 32
#define T_ 512
#define D_ 1024
#define H_ 1024
#define G4 4096
#define BT 16384
#define NWG 64

using bf16x8 = __attribute__((ext_vector_type(8))) short;
using f32x4  = __attribute__((ext_vector_type(4))) float;

__device__ __forceinline__ float sigm(float x) { return 1.0f / (1.0f + __expf(-x)); }

// ---- workspace layout (bytes) ----
#define OFF_BAR   0ull
#define OFF_HBUF  4096ull                      // [2][32][1024] bf16 = 131072
#define OFF_WHB   (OFF_HBUF + 131072ull)       // Wh bf16 [4096][1024] = 8388608
#define OFF_WXB   (OFF_WHB + 8388608ull)       // Wx bf16 = 8388608
#define OFF_INPB  (OFF_WXB + 8388608ull)       // inp bf16 [32][512][1024] = 33554432
#define OFF_BXH   (OFF_INPB + 33554432ull)     // bx+bh f32 [4096] = 16384
#define OFF_XG    (OFF_BXH + 16384ull)         // xg bf16 [16384][4096] = 134217728
#define WS_NEEDED (OFF_XG + 134217728ull)      // = 184700928

// ============ phase 1: convert inputs to bf16, fold biases ============
__global__ __launch_bounds__(256) void convert_all(
    const float* __restrict__ inp, const float* __restrict__ Wx,
    const float* __restrict__ bx, const float* __restrict__ Wh,
    const float* __restrict__ bh,
    __hip_bfloat16* __restrict__ inp_b, __hip_bfloat16* __restrict__ Wx_b,
    __hip_bfloat16* __restrict__ Wh_b, float* __restrict__ bxh)
{
    const int gid = blockIdx.x * 256 + threadIdx.x;   // 0 .. 1048575
    // inp: 16 elems/thread
    {
        const float4* s = (const float4*)inp + (size_t)gid * 4;
        #pragma unroll
        for (int v = 0; v < 4; ++v) {
            float4 f = s[v];
            size_t base = (size_t)gid * 16 + v * 4;
            inp_b[base + 0] = __float2bfloat16(f.x);
            inp_b[base + 1] = __float2bfloat16(f.y);
            inp_b[base + 2] = __float2bfloat16(f.z);
            inp_b[base + 3] = __float2bfloat16(f.w);
        }
    }
    // Wx / Wh: 4 elems/thread
    {
        float4 fx = ((const float4*)Wx)[gid];
        float4 fh = ((const float4*)Wh)[gid];
        size_t base = (size_t)gid * 4;
        Wx_b[base + 0] = __float2bfloat16(fx.x);
        Wx_b[base + 1] = __float2bfloat16(fx.y);
        Wx_b[base + 2] = __float2bfloat16(fx.z);
        Wx_b[base + 3] = __float2bfloat16(fx.w);
        Wh_b[base + 0] = __float2bfloat16(fh.x);
        Wh_b[base + 1] = __float2bfloat16(fh.y);
        Wh_b[base + 2] = __float2bfloat16(fh.z);
        Wh_b[base + 3] = __float2bfloat16(fh.w);
    }
    if (gid < G4) bxh[gid] = bx[gid] + bh[gid];
}

// ============ phase 2: xg = X @ Wx^T + (bx+bh), bf16 MFMA ============
// grid (BT/64, G4/64), block 256 (4 waves). Wave w computes rows [m0+16w, +16) x 64 cols.
__global__ __launch_bounds__(256) void xg_gemm(
    const __hip_bfloat16* __restrict__ X,    // [BT][D]
    const __hip_bfloat16* __restrict__ Wxb,  // [G4][D]
    const float* __restrict__ bxh,           // [G4]
    __hip_bfloat16* __restrict__ xg)         // [BT][G4]
{
    const int m0 = blockIdx.x * 64;
    const int n0 = blockIdx.y * 64;
    const int lane = threadIdx.x & 63;
    const int wave = threadIdx.x >> 6;
    const int l15 = lane & 15;
    const int kg = (lane >> 4) * 8;

    f32x4 acc[4] = {};
    const __hip_bfloat16* xrow = X + (size_t)(m0 + wave * 16 + l15) * D_;
    for (int k0 = 0; k0 < D_; k0 += 32) {
        bf16x8 a = *(const bf16x8*)(xrow + k0 + kg);
        #pragma unroll
        for (int n = 0; n < 4; ++n) {
            bf16x8 b = *(const bf16x8*)(Wxb + (size_t)(n0 + n * 16 + l15) * D_ + k0 + kg);
            acc[n] = __builtin_amdgcn_mfma_f32_16x16x32_bf16(a, b, acc[n], 0, 0, 0);
        }
    }
    const int r0 = m0 + wave * 16 + ((lane >> 4) << 2);
    #pragma unroll
    for (int n = 0; n < 4; ++n) {
        const int col = n0 + n * 16 + l15;
        const float bias = bxh[col];
        #pragma unroll
        for (int r = 0; r < 4; ++r)
            xg[(size_t)(r0 + r) * G4 + col] = __float2bfloat16(acc[n][r] + bias);
    }
}

// ============ phase 3: persistent recurrent scan ============
// 64 WGs x 512 threads; WG w owns h columns [w*16, w*16+16).
// LDS: Whs = 64 rows (4 gates x 16 jj) x 1024 k, bf16, XOR-swizzled (131072 B)
//      gbuf = [32 b][4 q][16 jj] f32 (8192 B)
// wave = (mwave 0..1) x (q 0..3): one 16x16 MFMA tile per wave per step.
// c-state lives in one register per thread (thread = (b, jj) pair).
__global__ __launch_bounds__(512) void lstm_scan(
    const __hip_bfloat16* __restrict__ xg,    // [BT][G4] (bias folded)
    const __hip_bfloat16* __restrict__ Whb,   // [G4][H]
    float* __restrict__ out,                  // [B][T][H]
    __hip_bfloat16* __restrict__ hbuf,        // [2][B][H]
    unsigned int* __restrict__ bar)
{
    extern __shared__ char smem[];
    float* gbuf = (float*)(smem + 131072);

    const int w    = blockIdx.x;
    const int tid  = threadIdx.x;
    const int lane = tid & 63;
    const int wave = tid >> 6;
    const int mwave = wave >> 2;       // 0..1
    const int q     = wave & 3;        // gate
    const int l15   = lane & 15;
    const int kg    = (lane >> 4) * 8;

    // ---- stage the 64 Wh rows {q*1024 + w*16 + jj} into LDS, swizzled ----
    for (int c = tid; c < 8192; c += 512) {           // 8192 x 16B chunks
        const int r  = c >> 7;                        // local row 0..63 = gq*16+jj
        const int ck = c & 127;                       // 16B chunk in row
        const int gq = r >> 4, gjj = r & 15;
        bf16x8 v = *(const bf16x8*)(Whb + (size_t)(gq * H_ + w * 16 + gjj) * H_ + ck * 8);
        *(bf16x8*)(smem + r * 2048 + ((ck * 16) ^ ((r & 7) << 4))) = v;
    }
    __syncthreads();

    // B-frag LDS address components for this wave's lane (row = q*16 + l15)
    const int brow  = q * 16 + l15;
    const int bbase = brow * 2048;
    const int bxor  = (brow & 7) << 4;

    // pointwise ownership
    const int pb  = tid >> 4;          // batch 0..31
    const int pjj = tid & 15;
    const int jcol = w * 16 + pjj;     // global h column
    float cst = 0.0f;

    // D-tile row base for this wave's lane
    const int dbr = mwave * 16 + ((lane >> 4) << 2);
    const int colg = q * 1024 + w * 16 + l15;   // xg/gate column for MFMA lanes

    for (int t = 0; t < T_; ++t) {
        // hoist xg loads (independent of h) to hide HBM latency under MFMA
        float xgv[4];
        #pragma unroll
        for (int r = 0; r < 4; ++r)
            xgv[r] = __bfloat162float(xg[(size_t)((dbr + r) * T_ + t) * G4 + colg]);

        f32x4 acc = {};
        if (t > 0) {
            const __hip_bfloat16* hrow =
                hbuf + (size_t)(((t & 1) ^ 1) * B_ + mwave * 16 + l15) * H_;
            for (int k0 = 0; k0 < H_; k0 += 32) {
                bf16x8 a = *(const bf16x8*)(hrow + k0 + kg);
                bf16x8 b = *(const bf16x8*)(smem + bbase + (((k0 + kg) << 1) ^ bxor));
                acc = __builtin_amdgcn_mfma_f32_16x16x32_bf16(a, b, acc, 0, 0, 0);
            }
        }
        #pragma unroll
        for (int r = 0; r < 4; ++r)
            gbuf[((dbr + r) * 4 + q) * 16 + l15] = acc[r] + xgv[r];
        __syncthreads();

        // pointwise gate update; c stays in a register
        {
            float gi = sigm(gbuf[(pb * 4 + 0) * 16 + pjj]);
            float gf = sigm(gbuf[(pb * 4 + 1) * 16 + pjj]);
            float gg = sigm(gbuf[(pb * 4 + 2) * 16 + pjj]);  // sigmoid cell gate, per reference
            float go = sigm(gbuf[(pb * 4 + 3) * 16 + pjj]);
            cst = cst * gf + gi * gg;
            float h = go * tanhf(cst);
            out[((size_t)pb * T_ + t) * H_ + jcol] = h;
            hbuf[(size_t)((t & 1) * B_ + pb) * H_ + jcol] = __float2bfloat16(h);
        }

        // grid barrier: publish h_t, wait for all WGs
        __syncthreads();
        if (tid == 0) {
            __threadfence();
            __hip_atomic_fetch_add(bar, 1u, __ATOMIC_RELEASE, __HIP_MEMORY_SCOPE_AGENT);
            const unsigned target = (unsigned)NWG * (t + 1);
            while (__hip_atomic_load(bar, __ATOMIC_ACQUIRE, __HIP_MEMORY_SCOPE_AGENT) < target)
                __builtin_amdgcn_s_sleep(1);
        }
        __syncthreads();
    }
}

// ============ fallback (round-1 slow path) if ws too small ============
__global__ __launch_bounds__(256) void lstm_step(
    const float* __restrict__ inp, const float* __restrict__ Wx,
    const float* __restrict__ bx, const float* __restrict__ Wh,
    const float* __restrict__ bh, float* __restrict__ out,
    float* __restrict__ c_state, int t)
{
    const int tid = threadIdx.x;
    const int lane = tid & 63;
    const int khalf = lane & 1;
    const int b = lane >> 1;
    const int j = blockIdx.x * 4 + (tid >> 6);
    const int k0 = khalf * (D_ / 2);
    float a0 = 0.f, a1 = 0.f, a2 = 0.f, a3 = 0.f;
    {
        const float* xrow = inp + ((size_t)b * T_ + t) * D_ + k0;
        const float* w0 = Wx + (size_t)(0 * H_ + j) * D_ + k0;
        const float* w1 = Wx + (size_t)(1 * H_ + j) * D_ + k0;
        const float* w2 = Wx + (size_t)(2 * H_ + j) * D_ + k0;
        const float* w3 = Wx + (size_t)(3 * H_ + j) * D_ + k0;
        for (int kk = 0; kk < D_ / 2; kk += 4) {
            float4 xv = *(const float4*)(xrow + kk);
            float4 v0 = *(const float4*)(w0 + kk), v1 = *(const float4*)(w1 + kk);
            float4 v2 = *(const float4*)(w2 + kk), v3 = *(const float4*)(w3 + kk);
            a0 = fmaf(xv.x, v0.x, fmaf(xv.y, v0.y, fmaf(xv.z, v0.z, fmaf(xv.w, v0.w, a0))));
            a1 = fmaf(xv.x, v1.x, fmaf(xv.y, v1.y, fmaf(xv.z, v1.z, fmaf(xv.w, v1.w, a1))));
            a2 = fmaf(xv.x, v2.x, fmaf(xv.y, v2.y, fmaf(xv.z, v2.z, fmaf(xv.w, v2.w, a2))));
            a3 = fmaf(xv.x, v3.x, fmaf(xv.y, v3.y, fmaf(xv.z, v3.z, fmaf(xv.w, v3.w, a3))));
        }
    }
    if (t > 0) {
        const float* hrow = out + ((size_t)b * T_ + (t - 1)) * H_ + k0;
        const float* w0 = Wh + (size_t)(0 * H_ + j) * H_ + k0;
        const float* w1 = Wh + (size_t)(1 * H_ + j) * H_ + k0;
        const float* w2 = Wh + (size_t)(2 * H_ + j) * H_ + k0;
        const float* w3 = Wh + (size_t)(3 * H_ + j) * H_ + k0;
        for (int kk = 0; kk < H_ / 2; kk += 4) {
            float4 hv = *(const float4*)(hrow + kk);
            float4 v0 = *(const float4*)(w0 + kk), v1 = *(const float4*)(w1 + kk);
            float4 v2 = *(const float4*)(w2 + kk), v3 = *(const float4*)(w3 + kk);
            a0 = fmaf(hv.x, v0.x, fmaf(hv.y, v0.y, fmaf(hv.z, v0.z, fmaf(hv.w, v0.w, a0))));
            a1 = fmaf(hv.x, v1.x, fmaf(hv.y, v1.y, fmaf(hv.z, v1.z, fmaf(hv.w, v1.w, a1))));
            a2 = fmaf(hv.x, v2.x, fmaf(hv.y, v2.y, fmaf(hv.z, v2.z, fmaf(hv.w, v2.w, a2))));
            a3 = fmaf(hv.x, v3.x, fmaf(hv.y, v3.y, fmaf(hv.z, v3.z, fmaf(hv.w, v3.w, a3))));
        }
    }
    a0 += __shfl_xor(a0, 1, 64); a1 += __shfl_xor(a1, 1, 64);
    a2 += __shfl_xor(a2, 1, 64); a3 += __shfl_xor(a3, 1, 64);
    if (khalf == 0) {
        float gi = sigm(a0 + bx[0 * H_ + j] + bh[0 * H_ + j]);
        float gf = sigm(a1 + bx[1 * H_ + j] + bh[1 * H_ + j]);
        float gg = sigm(a2 + bx[2 * H_ + j] + bh[2 * H_ + j]);
        float go = sigm(a3 + bx[3 * H_ + j] + bh[3 * H_ + j]);
        size_t ci = (size_t)b * H_ + j;
        float c = (t > 0) ? c_state[ci] : 0.0f;
        c = c * gf + gi * gg;
        c_state[ci] = c;
        out[((size_t)b * T_ + t) * H_ + j] = go * tanhf(c);
    }
}

extern "C" void kernel_launch(void* const* d_in, const int* in_sizes, int n_in,
                              void* d_out, int out_size, void* d_ws, size_t ws_size,
                              hipStream_t stream) {
    const float* inp = (const float*)d_in[0];
    const float* Wx  = (const float*)d_in[1];
    const float* bx  = (const float*)d_in[2];
    const float* Wh  = (const float*)d_in[3];
    const float* bh  = (const float*)d_in[4];
    float* out = (float*)d_out;
    char* ws = (char*)d_ws;

    if (ws_size < WS_NEEDED) {
        // fallback: slow but correct
        float* c_state = (float*)d_ws;
        for (int t = 0; t < T_; ++t)
            lstm_step<<<dim3(H_ / 4), dim3(256), 0, stream>>>(inp, Wx, bx, Wh, bh, out, c_state, t);
        return;
    }

    unsigned int*    bar   = (unsigned int*)(ws + OFF_BAR);
    __hip_bfloat16*  hbuf  = (__hip_bfloat16*)(ws + OFF_HBUF);
    __hip_bfloat16*  Whb   = (__hip_bfloat16*)(ws + OFF_WHB);
    __hip_bfloat16*  Wxb   = (__hip_bfloat16*)(ws + OFF_WXB);
    __hip_bfloat16*  inp_b = (__hip_bfloat16*)(ws + OFF_INPB);
    float*           bxh   = (float*)(ws + OFF_BXH);
    __hip_bfloat16*  xg    = (__hip_bfloat16*)(ws + OFF_XG);

    hipMemsetAsync(bar, 0, 256, stream);

    convert_all<<<dim3(4096), dim3(256), 0, stream>>>(inp, Wx, bx, Wh, bh, inp_b, Wxb, Whb, bxh);

    xg_gemm<<<dim3(BT / 64, G4 / 64), dim3(256), 0, stream>>>(inp_b, Wxb, bxh, xg);

    static bool attr_set = false;
    if (!attr_set) {
        hipFuncSetAttribute((const void*)lstm_scan,
                            hipFuncAttributeMaxDynamicSharedMemorySize, 139264);
        attr_set = true;
    }
    lstm_scan<<<dim3(NWG), dim3(512), 139264, stream>>>(xg, Whb, out, hbuf, bar);
}

// Round 3
// 6689.440 us; speedup vs baseline: 7.1838x; 1.1396x over previous
//
#include <hip/hip_runtime.h>
#include <hip/hip_bf16.h>
#include <math.h>

#define B_ 32
#define T_ 512
#define D_ 1024
#define H_ 1024
#define G4 4096
#define BT 16384
#define NWG 64

using bf16x8 = __attribute__((ext_vector_type(8))) short;
using f32x4  = __attribute__((ext_vector_type(4))) float;

__device__ __forceinline__ float sigm(float x) { return 1.0f / (1.0f + __expf(-x)); }

// ---- workspace layout (bytes) — identical footprint to round 2 (proven to fit) ----
#define OFF_FLG   0ull                         // 64 flags, 64B stride = 4096 B
#define OFF_HBUF  4096ull                      // [2][32][1024] bf16 = 131072
#define OFF_WHB   (OFF_HBUF + 131072ull)       // Wh bf16 [4096][1024] = 8388608
#define OFF_WXB   (OFF_WHB + 8388608ull)       // Wx bf16 = 8388608
#define OFF_INPB  (OFF_WXB + 8388608ull)       // inp bf16 [32][512][1024] = 33554432
#define OFF_BXH   (OFF_INPB + 33554432ull)     // bx+bh f32 [4096] = 16384
#define OFF_XG    (OFF_BXH + 16384ull)         // xg bf16 [T][B][G4] = 134217728
#define WS_NEEDED (OFF_XG + 134217728ull)

// ============ phase 1: convert inputs to bf16, fold biases ============
__global__ __launch_bounds__(256) void convert_all(
    const float* __restrict__ inp, const float* __restrict__ Wx,
    const float* __restrict__ bx, const float* __restrict__ Wh,
    const float* __restrict__ bh,
    __hip_bfloat16* __restrict__ inp_b, __hip_bfloat16* __restrict__ Wx_b,
    __hip_bfloat16* __restrict__ Wh_b, float* __restrict__ bxh)
{
    const int gid = blockIdx.x * 256 + threadIdx.x;   // 0 .. 1048575
    {
        const float4* s = (const float4*)inp + (size_t)gid * 4;
        #pragma unroll
        for (int v = 0; v < 4; ++v) {
            float4 f = s[v];
            size_t base = (size_t)gid * 16 + v * 4;
            inp_b[base + 0] = __float2bfloat16(f.x);
            inp_b[base + 1] = __float2bfloat16(f.y);
            inp_b[base + 2] = __float2bfloat16(f.z);
            inp_b[base + 3] = __float2bfloat16(f.w);
        }
    }
    {
        float4 fx = ((const float4*)Wx)[gid];
        float4 fh = ((const float4*)Wh)[gid];
        size_t base = (size_t)gid * 4;
        Wx_b[base + 0] = __float2bfloat16(fx.x);
        Wx_b[base + 1] = __float2bfloat16(fx.y);
        Wx_b[base + 2] = __float2bfloat16(fx.z);
        Wx_b[base + 3] = __float2bfloat16(fx.w);
        Wh_b[base + 0] = __float2bfloat16(fh.x);
        Wh_b[base + 1] = __float2bfloat16(fh.y);
        Wh_b[base + 2] = __float2bfloat16(fh.z);
        Wh_b[base + 3] = __float2bfloat16(fh.w);
    }
    if (gid < G4) bxh[gid] = bx[gid] + bh[gid];
}

// ============ phase 2: xg = X @ Wx^T + (bx+bh), transposed store [T][B][G4] ============
// grid (BT/128, G4/64), block 256 (4 waves). Each wave: 2 m-tiles x 4 n-tiles.
__global__ __launch_bounds__(256) void xg_gemm(
    const __hip_bfloat16* __restrict__ X,    // [BT][D], row = b*T + t
    const __hip_bfloat16* __restrict__ Wxb,  // [G4][D]
    const float* __restrict__ bxh,           // [G4]
    __hip_bfloat16* __restrict__ xg)         // [T][B][G4]
{
    const int m0 = blockIdx.x * 128;
    const int n0 = blockIdx.y * 64;
    const int lane = threadIdx.x & 63;
    const int wave = threadIdx.x >> 6;
    const int l15 = lane & 15;
    const int kg = (lane >> 4) * 8;

    f32x4 acc[2][4] = {};
    const __hip_bfloat16* xrow0 = X + (size_t)(m0 + wave * 16 + l15) * D_;
    const __hip_bfloat16* xrow1 = xrow0 + (size_t)64 * D_;
    for (int k0 = 0; k0 < D_; k0 += 32) {
        bf16x8 a0 = *(const bf16x8*)(xrow0 + k0 + kg);
        bf16x8 a1 = *(const bf16x8*)(xrow1 + k0 + kg);
        #pragma unroll
        for (int n = 0; n < 4; ++n) {
            bf16x8 b = *(const bf16x8*)(Wxb + (size_t)(n0 + n * 16 + l15) * D_ + k0 + kg);
            acc[0][n] = __builtin_amdgcn_mfma_f32_16x16x32_bf16(a0, b, acc[0][n], 0, 0, 0);
            acc[1][n] = __builtin_amdgcn_mfma_f32_16x16x32_bf16(a1, b, acc[1][n], 0, 0, 0);
        }
    }
    #pragma unroll
    for (int g = 0; g < 2; ++g) {
        const int r0 = m0 + g * 64 + wave * 16 + ((lane >> 4) << 2);
        #pragma unroll
        for (int n = 0; n < 4; ++n) {
            const int col = n0 + n * 16 + l15;
            const float bias = bxh[col];
            #pragma unroll
            for (int r = 0; r < 4; ++r) {
                const int row = r0 + r;                 // = b*T + t
                const int bb = row >> 9, tt = row & 511;
                xg[((size_t)tt * B_ + bb) * G4 + col] = __float2bfloat16(acc[g][n][r] + bias);
            }
        }
    }
}

// ============ phase 3: persistent recurrent scan ============
// 64 WGs x 512 threads; WG w owns h columns [w*16, w*16+16).
// Wh fragments live ENTIRELY in registers (128 VGPR/lane). LDS = padded gate buffer only.
// Grid sync = one-sided flag barrier: per-WG release store + wave0 64-lane poll.
__global__ __launch_bounds__(512, 2) void lstm_scan(
    const __hip_bfloat16* __restrict__ xg,    // [T][B][G4] (bias folded)
    const __hip_bfloat16* __restrict__ Whb,   // [G4][H]
    float* __restrict__ out,                  // [B][T][H]
    __hip_bfloat16* __restrict__ hbuf,        // [2][B][H]
    unsigned int* __restrict__ flags)         // [NWG] at 16-uint (64B) stride
{
    __shared__ float gbuf[32 * 4 * 17 + 12];  // [b][q][17] padded vs bank conflicts

    const int w    = blockIdx.x;
    const int tid  = threadIdx.x;
    const int lane = tid & 63;
    const int wave = tid >> 6;
    const int mwave = wave >> 2;       // 0..1
    const int q     = wave & 3;        // gate
    const int l15   = lane & 15;
    const int kg    = (lane >> 4) * 8;

    // ---- load this wave's Wh B-fragments into registers (once) ----
    // B-frag row = gate-col = q*1024 + w*16 + l15; 32 k-steps x 8 bf16 = 128 VGPRs.
    bf16x8 bfrag[32];
    {
        const __hip_bfloat16* wrow = Whb + (size_t)(q * 1024 + w * 16 + l15) * H_;
        #pragma unroll
        for (int i = 0; i < 32; ++i)
            bfrag[i] = *(const bf16x8*)(wrow + i * 32 + kg);
    }

    // pointwise ownership: thread = (batch, jj)
    const int pb  = tid >> 4;          // 0..31
    const int pjj = tid & 15;
    const int jcol = w * 16 + pjj;
    float cst = 0.0f;

    const int dbr  = mwave * 16 + ((lane >> 4) << 2);   // batch-row base of D-tile
    const int colg = q * 1024 + w * 16 + l15;           // gate column for MFMA lanes

    for (int t = 0; t < T_; ++t) {
        // prefetch xg (independent of h) — overlaps the flag wait
        float xgv[4];
        #pragma unroll
        for (int r = 0; r < 4; ++r)
            xgv[r] = __bfloat162float(xg[((size_t)t * B_ + dbr + r) * G4 + colg]);

        if (t > 0) {
            if (wave == 0) {
                const unsigned int* fp = flags + lane * 16;   // lane -> WG
                while (__hip_atomic_load(fp, __ATOMIC_RELAXED, __HIP_MEMORY_SCOPE_AGENT)
                       < (unsigned)t)
                    __builtin_amdgcn_s_sleep(2);
                __threadfence();   // acquire: invalidate stale h lines
            }
            __syncthreads();
        }

        f32x4 acc0 = {}, acc1 = {};
        if (t > 0) {
            const __hip_bfloat16* hrow =
                hbuf + (size_t)((((t - 1) & 1)) * B_ + mwave * 16 + l15) * H_;
            #pragma unroll
            for (int i = 0; i < 16; ++i) {
                bf16x8 a0 = *(const bf16x8*)(hrow + i * 64 + kg);
                bf16x8 a1 = *(const bf16x8*)(hrow + i * 64 + 32 + kg);
                acc0 = __builtin_amdgcn_mfma_f32_16x16x32_bf16(a0, bfrag[2 * i + 0], acc0, 0, 0, 0);
                acc1 = __builtin_amdgcn_mfma_f32_16x16x32_bf16(a1, bfrag[2 * i + 1], acc1, 0, 0, 0);
            }
        }
        #pragma unroll
        for (int r = 0; r < 4; ++r)
            gbuf[((dbr + r) * 4 + q) * 17 + l15] = acc0[r] + acc1[r] + xgv[r];
        __syncthreads();

        // pointwise gate update; c stays in a register
        {
            float gi = sigm(gbuf[(pb * 4 + 0) * 17 + pjj]);
            float gf = sigm(gbuf[(pb * 4 + 1) * 17 + pjj]);
            float gg = sigm(gbuf[(pb * 4 + 2) * 17 + pjj]);  // sigmoid cell gate, per reference
            float go = sigm(gbuf[(pb * 4 + 3) * 17 + pjj]);
            cst = cst * gf + gi * gg;
            float h = go * tanhf(cst);
            out[((size_t)pb * T_ + t) * H_ + jcol] = h;
            hbuf[(size_t)((t & 1) * B_ + pb) * H_ + jcol] = __float2bfloat16(h);
        }
        __syncthreads();   // all h writes done; also guards gbuf reuse

        if (t < T_ - 1 && tid == 0) {
            __threadfence();   // release: push this WG's h writes to agent scope
            __hip_atomic_store(flags + w * 16, (unsigned)(t + 1),
                               __ATOMIC_RELAXED, __HIP_MEMORY_SCOPE_AGENT);
        }
    }
}

// ============ fallback (round-1 slow path) if ws too small ============
__global__ __launch_bounds__(256) void lstm_step(
    const float* __restrict__ inp, const float* __restrict__ Wx,
    const float* __restrict__ bx, const float* __restrict__ Wh,
    const float* __restrict__ bh, float* __restrict__ out,
    float* __restrict__ c_state, int t)
{
    const int tid = threadIdx.x;
    const int lane = tid & 63;
    const int khalf = lane & 1;
    const int b = lane >> 1;
    const int j = blockIdx.x * 4 + (tid >> 6);
    const int k0 = khalf * (D_ / 2);
    float a0 = 0.f, a1 = 0.f, a2 = 0.f, a3 = 0.f;
    {
        const float* xrow = inp + ((size_t)b * T_ + t) * D_ + k0;
        const float* w0 = Wx + (size_t)(0 * H_ + j) * D_ + k0;
        const float* w1 = Wx + (size_t)(1 * H_ + j) * D_ + k0;
        const float* w2 = Wx + (size_t)(2 * H_ + j) * D_ + k0;
        const float* w3 = Wx + (size_t)(3 * H_ + j) * D_ + k0;
        for (int kk = 0; kk < D_ / 2; kk += 4) {
            float4 xv = *(const float4*)(xrow + kk);
            float4 v0 = *(const float4*)(w0 + kk), v1 = *(const float4*)(w1 + kk);
            float4 v2 = *(const float4*)(w2 + kk), v3 = *(const float4*)(w3 + kk);
            a0 = fmaf(xv.x, v0.x, fmaf(xv.y, v0.y, fmaf(xv.z, v0.z, fmaf(xv.w, v0.w, a0))));
            a1 = fmaf(xv.x, v1.x, fmaf(xv.y, v1.y, fmaf(xv.z, v1.z, fmaf(xv.w, v1.w, a1))));
            a2 = fmaf(xv.x, v2.x, fmaf(xv.y, v2.y, fmaf(xv.z, v2.z, fmaf(xv.w, v2.w, a2))));
            a3 = fmaf(xv.x, v3.x, fmaf(xv.y, v3.y, fmaf(xv.z, v3.z, fmaf(xv.w, v3.w, a3))));
        }
    }
    if (t > 0) {
        const float* hrow = out + ((size_t)b * T_ + (t - 1)) * H_ + k0;
        const float* w0 = Wh + (size_t)(0 * H_ + j) * H_ + k0;
        const float* w1 = Wh + (size_t)(1 * H_ + j) * H_ + k0;
        const float* w2 = Wh + (size_t)(2 * H_ + j) * H_ + k0;
        const float* w3 = Wh + (size_t)(3 * H_ + j) * H_ + k0;
        for (int kk = 0; kk < H_ / 2; kk += 4) {
            float4 hv = *(const float4*)(hrow + kk);
            float4 v0 = *(const float4*)(w0 + kk), v1 = *(const float4*)(w1 + kk);
            float4 v2 = *(const float4*)(w2 + kk), v3 = *(const float4*)(w3 + kk);
            a0 = fmaf(hv.x, v0.x, fmaf(hv.y, v0.y, fmaf(hv.z, v0.z, fmaf(hv.w, v0.w, a0))));
            a1 = fmaf(hv.x, v1.x, fmaf(hv.y, v1.y, fmaf(hv.z, v1.z, fmaf(hv.w, v1.w, a1))));
            a2 = fmaf(hv.x, v2.x, fmaf(hv.y, v2.y, fmaf(hv.z, v2.z, fmaf(hv.w, v2.w, a2))));
            a3 = fmaf(hv.x, v3.x, fmaf(hv.y, v3.y, fmaf(hv.z, v3.z, fmaf(hv.w, v3.w, a3))));
        }
    }
    a0 += __shfl_xor(a0, 1, 64); a1 += __shfl_xor(a1, 1, 64);
    a2 += __shfl_xor(a2, 1, 64); a3 += __shfl_xor(a3, 1, 64);
    if (khalf == 0) {
        float gi = sigm(a0 + bx[0 * H_ + j] + bh[0 * H_ + j]);
        float gf = sigm(a1 + bx[1 * H_ + j] + bh[1 * H_ + j]);
        float gg = sigm(a2 + bx[2 * H_ + j] + bh[2 * H_ + j]);
        float go = sigm(a3 + bx[3 * H_ + j] + bh[3 * H_ + j]);
        size_t ci = (size_t)b * H_ + j;
        float c = (t > 0) ? c_state[ci] : 0.0f;
        c = c * gf + gi * gg;
        c_state[ci] = c;
        out[((size_t)b * T_ + t) * H_ + j] = go * tanhf(c);
    }
}

extern "C" void kernel_launch(void* const* d_in, const int* in_sizes, int n_in,
                              void* d_out, int out_size, void* d_ws, size_t ws_size,
                              hipStream_t stream) {
    const float* inp = (const float*)d_in[0];
    const float* Wx  = (const float*)d_in[1];
    const float* bx  = (const float*)d_in[2];
    const float* Wh  = (const float*)d_in[3];
    const float* bh  = (const float*)d_in[4];
    float* out = (float*)d_out;
    char* ws = (char*)d_ws;

    if (ws_size < WS_NEEDED) {
        float* c_state = (float*)d_ws;
        for (int t = 0; t < T_; ++t)
            lstm_step<<<dim3(H_ / 4), dim3(256), 0, stream>>>(inp, Wx, bx, Wh, bh, out, c_state, t);
        return;
    }

    unsigned int*    flags = (unsigned int*)(ws + OFF_FLG);
    __hip_bfloat16*  hbuf  = (__hip_bfloat16*)(ws + OFF_HBUF);
    __hip_bfloat16*  Whb   = (__hip_bfloat16*)(ws + OFF_WHB);
    __hip_bfloat16*  Wxb   = (__hip_bfloat16*)(ws + OFF_WXB);
    __hip_bfloat16*  inp_b = (__hip_bfloat16*)(ws + OFF_INPB);
    float*           bxh   = (float*)(ws + OFF_BXH);
    __hip_bfloat16*  xg    = (__hip_bfloat16*)(ws + OFF_XG);

    hipMemsetAsync(flags, 0, 4096, stream);

    convert_all<<<dim3(4096), dim3(256), 0, stream>>>(inp, Wx, bx, Wh, bh, inp_b, Wxb, Whb, bxh);

    xg_gemm<<<dim3(BT / 128, G4 / 64), dim3(256), 0, stream>>>(inp_b, Wxb, bxh, xg);

    lstm_scan<<<dim3(NWG), dim3(512), 0, stream>>>(xg, Whb, out, hbuf, flags);
}

// Round 4
// 4390.213 us; speedup vs baseline: 10.9460x; 1.5237x over previous
//
#include <hip/hip_runtime.h>
#include <hip/hip_bf16.h>
#include <math.h>

#define B_ 32
#define T_ 512
#define D_ 1024
#define H_ 1024
#define G4 4096
#define BT 16384
#define NWG 64

using bf16x8 = __attribute__((ext_vector_type(8))) short;
using f32x4  = __attribute__((ext_vector_type(4))) float;
typedef unsigned long long u64;

__device__ __forceinline__ float sigm(float x) { return 1.0f / (1.0f + __expf(-x)); }

// ---- workspace layout (bytes) ----
#define OFF_FLG   0ull                         // 64 flags, 64B stride = 4096 B
#define OFF_HBUF  4096ull                      // [2][32][1024] bf16 = 131072
#define OFF_WHB   (OFF_HBUF + 131072ull)       // Wh bf16 [4096][1024] = 8388608
#define OFF_WXB   (OFF_WHB + 8388608ull)       // Wx bf16 = 8388608
#define OFF_INPB  (OFF_WXB + 8388608ull)       // inp bf16 [32][512][1024] = 33554432
#define OFF_BXH   (OFF_INPB + 33554432ull)     // bx+bh f32 [4096] = 16384
#define OFF_XG    (OFF_BXH + 16384ull)         // xg bf16 [T][4][NWG][32][16] = 134217728
#define WS_NEEDED (OFF_XG + 134217728ull)

// ============ phase 1: convert inputs to bf16, fold biases ============
__global__ __launch_bounds__(256) void convert_all(
    const float* __restrict__ inp, const float* __restrict__ Wx,
    const float* __restrict__ bx, const float* __restrict__ Wh,
    const float* __restrict__ bh,
    __hip_bfloat16* __restrict__ inp_b, __hip_bfloat16* __restrict__ Wx_b,
    __hip_bfloat16* __restrict__ Wh_b, float* __restrict__ bxh)
{
    const int gid = blockIdx.x * 256 + threadIdx.x;   // 0 .. 1048575
    {
        const float4* s = (const float4*)inp + (size_t)gid * 4;
        #pragma unroll
        for (int v = 0; v < 4; ++v) {
            float4 f = s[v];
            size_t base = (size_t)gid * 16 + v * 4;
            inp_b[base + 0] = __float2bfloat16(f.x);
            inp_b[base + 1] = __float2bfloat16(f.y);
            inp_b[base + 2] = __float2bfloat16(f.z);
            inp_b[base + 3] = __float2bfloat16(f.w);
        }
    }
    {
        float4 fx = ((const float4*)Wx)[gid];
        float4 fh = ((const float4*)Wh)[gid];
        size_t base = (size_t)gid * 4;
        Wx_b[base + 0] = __float2bfloat16(fx.x);
        Wx_b[base + 1] = __float2bfloat16(fx.y);
        Wx_b[base + 2] = __float2bfloat16(fx.z);
        Wx_b[base + 3] = __float2bfloat16(fx.w);
        Wh_b[base + 0] = __float2bfloat16(fh.x);
        Wh_b[base + 1] = __float2bfloat16(fh.y);
        Wh_b[base + 2] = __float2bfloat16(fh.z);
        Wh_b[base + 3] = __float2bfloat16(fh.w);
    }
    if (gid < G4) bxh[gid] = bx[gid] + bh[gid];
}

// ============ phase 2: xg = X @ Wx^T + (bx+bh), store [T][4][NWG][32][16] ============
__global__ __launch_bounds__(256) void xg_gemm(
    const __hip_bfloat16* __restrict__ X,    // [BT][D], row = b*T + t
    const __hip_bfloat16* __restrict__ Wxb,  // [G4][D]
    const float* __restrict__ bxh,           // [G4]
    __hip_bfloat16* __restrict__ xg)         // [T][4][NWG][32][16]
{
    const int m0 = blockIdx.x * 128;
    const int n0 = blockIdx.y * 64;
    const int lane = threadIdx.x & 63;
    const int wave = threadIdx.x >> 6;
    const int l15 = lane & 15;
    const int kg = (lane >> 4) * 8;

    f32x4 acc[2][4] = {};
    const __hip_bfloat16* xrow0 = X + (size_t)(m0 + wave * 16 + l15) * D_;
    const __hip_bfloat16* xrow1 = xrow0 + (size_t)64 * D_;
    for (int k0 = 0; k0 < D_; k0 += 32) {
        bf16x8 a0 = *(const bf16x8*)(xrow0 + k0 + kg);
        bf16x8 a1 = *(const bf16x8*)(xrow1 + k0 + kg);
        #pragma unroll
        for (int n = 0; n < 4; ++n) {
            bf16x8 b = *(const bf16x8*)(Wxb + (size_t)(n0 + n * 16 + l15) * D_ + k0 + kg);
            acc[0][n] = __builtin_amdgcn_mfma_f32_16x16x32_bf16(a0, b, acc[0][n], 0, 0, 0);
            acc[1][n] = __builtin_amdgcn_mfma_f32_16x16x32_bf16(a1, b, acc[1][n], 0, 0, 0);
        }
    }
    #pragma unroll
    for (int g = 0; g < 2; ++g) {
        const int r0 = m0 + g * 64 + wave * 16 + ((lane >> 4) << 2);
        #pragma unroll
        for (int n = 0; n < 4; ++n) {
            const int col = n0 + n * 16 + l15;
            const int qq  = col >> 10;
            const int ww  = (col >> 4) & 63;
            const int jj  = col & 15;
            const float bias = bxh[col];
            #pragma unroll
            for (int r = 0; r < 4; ++r) {
                const int row = r0 + r;                 // = b*T + t
                const int bb = row >> 9, tt = row & 511;
                xg[((((size_t)tt * 4 + qq) * NWG + ww) * 32 + bb) * 16 + jj] =
                    __float2bfloat16(acc[g][n][r] + bias);
            }
        }
    }
}

// ============ phase 3: persistent recurrent scan (fence-free) ============
// 64 WGs x 512 threads; WG w owns h columns [w*16, w*16+16).
// All cross-WG data moves via relaxed AGENT atomics (sc0/sc1 coherent, no cache flush).
// Wh fragments pinned in registers via atomic loads (non-rematerializable).
// LDS (64 KB static): h-stage [32][2048B] XOR-swizzled; gbuf aliases offset 0.
__global__ __launch_bounds__(512, 2) void lstm_scan(
    const __hip_bfloat16* __restrict__ xg,    // [T][4][NWG][32][16] (bias folded)
    const __hip_bfloat16* __restrict__ Whb,   // [G4][H]
    float* __restrict__ out,                  // [B][T][H]
    __hip_bfloat16* __restrict__ hbuf,        // [2][B][H]
    unsigned int* __restrict__ flags)         // [NWG] at 16-uint (64B) stride
{
    __shared__ char smem[65536];
    float* gbuf = (float*)smem;               // aliased over h-stage (barrier-separated)

    const int w    = blockIdx.x;
    const int tid  = threadIdx.x;
    const int lane = tid & 63;
    const int wave = tid >> 6;
    const int mwave = wave >> 2;       // 0..1
    const int q     = wave & 3;        // gate
    const int l15   = lane & 15;
    const int kg    = (lane >> 4) * 8;

    // ---- pin this wave's Wh B-fragments in registers (atomic loads can't be resunk) ----
    bf16x8 bfrag[32];
    {
        const char* wrow = (const char*)(Whb + (size_t)(q * 1024 + w * 16 + l15) * H_);
        #pragma unroll
        for (int i = 0; i < 32; ++i) {
            u64 lo = __hip_atomic_load((const u64*)(wrow + (i * 32 + kg) * 2),
                                       __ATOMIC_RELAXED, __HIP_MEMORY_SCOPE_AGENT);
            u64 hi = __hip_atomic_load((const u64*)(wrow + (i * 32 + kg) * 2 + 8),
                                       __ATOMIC_RELAXED, __HIP_MEMORY_SCOPE_AGENT);
            union { u64 qv[2]; bf16x8 v; } u;
            u.qv[0] = lo; u.qv[1] = hi;
            bfrag[i] = u.v;
        }
    }

    // pointwise ownership: thread = (batch, jj)
    const int pb  = tid >> 4;          // 0..31
    const int pjj = tid & 15;
    const int jcol = w * 16 + pjj;
    float cst = 0.0f;

    const int dbr  = mwave * 16 + ((lane >> 4) << 2);   // batch-row base of D-tile
    // A-frag LDS address components (row = batch = mwave*16 + l15)
    const int arow = mwave * 16 + l15;
    const int abase = arow * 2048;
    const int axor  = (arow & 7) << 4;
    // h-stage ownership: quarter-wave per row
    const int srow = wave * 4 + (lane >> 4);            // 0..31
    const int ql   = lane & 15;

    for (int t = 0; t < T_; ++t) {
        // xg prefetch (cached loads, contiguous per-WG slab) — independent of h
        float xgv[4];
        {
            const size_t sbase = (((size_t)t * 4 + q) * NWG + w) * 512;
            #pragma unroll
            for (int r = 0; r < 4; ++r)
                xgv[r] = __bfloat162float(xg[sbase + (dbr + r) * 16 + l15]);
        }

        f32x4 acc0 = {}, acc1 = {};
        if (t > 0) {
            // ---- wait for all WGs to publish h_{t-1} (one-sided, no fence) ----
            if (wave == 0) {
                const unsigned int* fp = flags + lane * 16;
                while (__hip_atomic_load(fp, __ATOMIC_RELAXED, __HIP_MEMORY_SCOPE_AGENT)
                       < (unsigned)t)
                    __builtin_amdgcn_s_sleep(1);
            }
            __syncthreads();

            // ---- stage h_{t-1} into LDS (coherent u64 loads, XOR-swizzled writes) ----
            {
                const u64* src = (const u64*)(hbuf + ((size_t)((t - 1) & 1) * B_ + srow) * H_);
                #pragma unroll
                for (int j = 0; j < 16; ++j) {
                    u64 v = __hip_atomic_load(src + ql + j * 16,
                                              __ATOMIC_RELAXED, __HIP_MEMORY_SCOPE_AGENT);
                    *(u64*)(smem + srow * 2048 + (((ql + j * 16) * 8) ^ ((srow & 7) << 4))) = v;
                }
            }
            __syncthreads();

            // ---- 32 MFMAs: acc = h_{t-1} @ Wh^T (two chains) ----
            #pragma unroll
            for (int i = 0; i < 16; ++i) {
                bf16x8 a0 = *(const bf16x8*)(smem + abase + (((i * 64 + kg) * 2) ^ axor));
                bf16x8 a1 = *(const bf16x8*)(smem + abase + (((i * 64 + 32 + kg) * 2) ^ axor));
                acc0 = __builtin_amdgcn_mfma_f32_16x16x32_bf16(a0, bfrag[2 * i + 0], acc0, 0, 0, 0);
                acc1 = __builtin_amdgcn_mfma_f32_16x16x32_bf16(a1, bfrag[2 * i + 1], acc1, 0, 0, 0);
            }
            __syncthreads();   // all LDS h reads done -> safe to overwrite with gbuf
        }

        #pragma unroll
        for (int r = 0; r < 4; ++r)
            gbuf[((dbr + r) * 4 + q) * 17 + l15] = acc0[r] + acc1[r] + xgv[r];
        __syncthreads();

        // ---- pointwise gate update; c stays in a register ----
        {
            float gi = sigm(gbuf[(pb * 4 + 0) * 17 + pjj]);
            float gf = sigm(gbuf[(pb * 4 + 1) * 17 + pjj]);
            float gg = sigm(gbuf[(pb * 4 + 2) * 17 + pjj]);  // sigmoid cell gate, per reference
            float go = sigm(gbuf[(pb * 4 + 3) * 17 + pjj]);
            cst = cst * gf + gi * gg;
            float h = go * tanhf(cst);
            out[((size_t)pb * T_ + t) * H_ + jcol] = h;
            __hip_bfloat16 hb = __float2bfloat16(h);
            unsigned short hbits;
            __builtin_memcpy(&hbits, &hb, 2);
            __hip_atomic_store((unsigned short*)(hbuf + ((size_t)(t & 1) * B_ + pb) * H_ + jcol),
                               hbits, __ATOMIC_RELAXED, __HIP_MEMORY_SCOPE_AGENT);
        }
        // __syncthreads drains each wave's vmcnt(0) before s_barrier -> all h stores
        // are acked at the coherence point before tid 0 publishes the flag.
        __syncthreads();
        if (t < T_ - 1 && tid == 0)
            __hip_atomic_store(flags + w * 16, (unsigned)(t + 1),
                               __ATOMIC_RELAXED, __HIP_MEMORY_SCOPE_AGENT);
    }
}

// ============ fallback (round-1 slow path) if ws too small ============
__global__ __launch_bounds__(256) void lstm_step(
    const float* __restrict__ inp, const float* __restrict__ Wx,
    const float* __restrict__ bx, const float* __restrict__ Wh,
    const float* __restrict__ bh, float* __restrict__ out,
    float* __restrict__ c_state, int t)
{
    const int tid = threadIdx.x;
    const int lane = tid & 63;
    const int khalf = lane & 1;
    const int b = lane >> 1;
    const int j = blockIdx.x * 4 + (tid >> 6);
    const int k0 = khalf * (D_ / 2);
    float a0 = 0.f, a1 = 0.f, a2 = 0.f, a3 = 0.f;
    {
        const float* xrow = inp + ((size_t)b * T_ + t) * D_ + k0;
        const float* w0 = Wx + (size_t)(0 * H_ + j) * D_ + k0;
        const float* w1 = Wx + (size_t)(1 * H_ + j) * D_ + k0;
        const float* w2 = Wx + (size_t)(2 * H_ + j) * D_ + k0;
        const float* w3 = Wx + (size_t)(3 * H_ + j) * D_ + k0;
        for (int kk = 0; kk < D_ / 2; kk += 4) {
            float4 xv = *(const float4*)(xrow + kk);
            float4 v0 = *(const float4*)(w0 + kk), v1 = *(const float4*)(w1 + kk);
            float4 v2 = *(const float4*)(w2 + kk), v3 = *(const float4*)(w3 + kk);
            a0 = fmaf(xv.x, v0.x, fmaf(xv.y, v0.y, fmaf(xv.z, v0.z, fmaf(xv.w, v0.w, a0))));
            a1 = fmaf(xv.x, v1.x, fmaf(xv.y, v1.y, fmaf(xv.z, v1.z, fmaf(xv.w, v1.w, a1))));
            a2 = fmaf(xv.x, v2.x, fmaf(xv.y, v2.y, fmaf(xv.z, v2.z, fmaf(xv.w, v2.w, a2))));
            a3 = fmaf(xv.x, v3.x, fmaf(xv.y, v3.y, fmaf(xv.z, v3.z, fmaf(xv.w, v3.w, a3))));
        }
    }
    if (t > 0) {
        const float* hrow = out + ((size_t)b * T_ + (t - 1)) * H_ + k0;
        const float* w0 = Wh + (size_t)(0 * H_ + j) * H_ + k0;
        const float* w1 = Wh + (size_t)(1 * H_ + j) * H_ + k0;
        const float* w2 = Wh + (size_t)(2 * H_ + j) * H_ + k0;
        const float* w3 = Wh + (size_t)(3 * H_ + j) * H_ + k0;
        for (int kk = 0; kk < H_ / 2; kk += 4) {
            float4 hv = *(const float4*)(hrow + kk);
            float4 v0 = *(const float4*)(w0 + kk), v1 = *(const float4*)(w1 + kk);
            float4 v2 = *(const float4*)(w2 + kk), v3 = *(const float4*)(w3 + kk);
            a0 = fmaf(hv.x, v0.x, fmaf(hv.y, v0.y, fmaf(hv.z, v0.z, fmaf(hv.w, v0.w, a0))));
            a1 = fmaf(hv.x, v1.x, fmaf(hv.y, v1.y, fmaf(hv.z, v1.z, fmaf(hv.w, v1.w, a1))));
            a2 = fmaf(hv.x, v2.x, fmaf(hv.y, v2.y, fmaf(hv.z, v2.z, fmaf(hv.w, v2.w, a2))));
            a3 = fmaf(hv.x, v3.x, fmaf(hv.y, v3.y, fmaf(hv.z, v3.z, fmaf(hv.w, v3.w, a3))));
        }
    }
    a0 += __shfl_xor(a0, 1, 64); a1 += __shfl_xor(a1, 1, 64);
    a2 += __shfl_xor(a2, 1, 64); a3 += __shfl_xor(a3, 1, 64);
    if (khalf == 0) {
        float gi = sigm(a0 + bx[0 * H_ + j] + bh[0 * H_ + j]);
        float gf = sigm(a1 + bx[1 * H_ + j] + bh[1 * H_ + j]);
        float gg = sigm(a2 + bx[2 * H_ + j] + bh[2 * H_ + j]);
        float go = sigm(a3 + bx[3 * H_ + j] + bh[3 * H_ + j]);
        size_t ci = (size_t)b * H_ + j;
        float c = (t > 0) ? c_state[ci] : 0.0f;
        c = c * gf + gi * gg;
        c_state[ci] = c;
        out[((size_t)b * T_ + t) * H_ + j] = go * tanhf(c);
    }
}

extern "C" void kernel_launch(void* const* d_in, const int* in_sizes, int n_in,
                              void* d_out, int out_size, void* d_ws, size_t ws_size,
                              hipStream_t stream) {
    const float* inp = (const float*)d_in[0];
    const float* Wx  = (const float*)d_in[1];
    const float* bx  = (const float*)d_in[2];
    const float* Wh  = (const float*)d_in[3];
    const float* bh  = (const float*)d_in[4];
    float* out = (float*)d_out;
    char* ws = (char*)d_ws;

    if (ws_size < WS_NEEDED) {
        float* c_state = (float*)d_ws;
        for (int t = 0; t < T_; ++t)
            lstm_step<<<dim3(H_ / 4), dim3(256), 0, stream>>>(inp, Wx, bx, Wh, bh, out, c_state, t);
        return;
    }

    unsigned int*    flags = (unsigned int*)(ws + OFF_FLG);
    __hip_bfloat16*  hbuf  = (__hip_bfloat16*)(ws + OFF_HBUF);
    __hip_bfloat16*  Whb   = (__hip_bfloat16*)(ws + OFF_WHB);
    __hip_bfloat16*  Wxb   = (__hip_bfloat16*)(ws + OFF_WXB);
    __hip_bfloat16*  inp_b = (__hip_bfloat16*)(ws + OFF_INPB);
    float*           bxh   = (float*)(ws + OFF_BXH);
    __hip_bfloat16*  xg    = (__hip_bfloat16*)(ws + OFF_XG);

    hipMemsetAsync(flags, 0, 4096, stream);

    convert_all<<<dim3(4096), dim3(256), 0, stream>>>(inp, Wx, bx, Wh, bh, inp_b, Wxb, Whb, bxh);

    xg_gemm<<<dim3(BT / 128, G4 / 64), dim3(256), 0, stream>>>(inp_b, Wxb, bxh, xg);

    lstm_scan<<<dim3(NWG), dim3(512), 0, stream>>>(xg, Whb, out, hbuf, flags);
}